// Round 8
// baseline (150.368 us; speedup 1.0000x reference)
//
#include <hip/hip_runtime.h>
#include <hip/hip_bf16.h>
#include <math.h>

// EulerCausalAttention on MI355X (gfx950).
// prep (euler features -> Q/K in MFMA-FRAGMENT layout, x->bf16) ; wconv ;
// V-GEMM (epilogue writes V in PV-B-fragment layout) ;
// BARRIER-FREE causal flash attention: 1024 independent 1-wave blocks, no LDS,
// K/V streamed fragment-major from (per-XCD-resident) L2 ;
// out-GEMM. All matmuls bf16 MFMA 16x16x32, f32 accumulate.
//
// Fragment layouts (verified algebra identical to the passing round-5 kernel):
//  QKf[bh][s16][e][lane(g,lo)][8] = T[s16*16+lo][e*32+g*8+j]   (e: 0,1=cos 2,3=sin)
//  Vf[bh][kt][kk*4+nd][lane(g,lo)][j] = V[nd*16+lo][kt*64 + 32kk + 16(j>>2) + 4g + (j&3)]

typedef __attribute__((ext_vector_type(8))) __bf16 bf16x8;
typedef __attribute__((ext_vector_type(4))) float f32x4;
typedef unsigned short ushort_t;
typedef unsigned int uint_t;

#define LUTC 651.8986469044033f       // 4096 / (2*pi)
#define ANG 0.0015339807878856412f    // 2*pi / 4096
#define QSCL 0.12751743590489435f     // log2(e) / sqrt(128)  (folded into Q)

__device__ __forceinline__ float fast_exp2(float x) {
#if __has_builtin(__builtin_amdgcn_exp2f)
  return __builtin_amdgcn_exp2f(x);
#else
  return exp2f(x);
#endif
}

__device__ __forceinline__ ushort_t f2bf(float f) {
  union { __bf16 b; ushort_t u; } cv;
  cv.b = (__bf16)f;
  return cv.u;
}

__device__ __forceinline__ void store8(ushort_t* p, const ushort_t v[8]) {
  uint4 u;
  u.x = (uint_t)v[0] | ((uint_t)v[1] << 16);
  u.y = (uint_t)v[2] | ((uint_t)v[3] << 16);
  u.z = (uint_t)v[4] | ((uint_t)v[5] << 16);
  u.w = (uint_t)v[6] | ((uint_t)v[7] << 16);
  *(uint4*)p = u;
}

__device__ __forceinline__ void gl_lds16(const void* g, void* l) {
  __builtin_amdgcn_global_load_lds(
      (__attribute__((address_space(1))) void*)(g),
      (__attribute__((address_space(3))) void*)(l),
      16, 0, 0);
}

// ---------------------------------------------------------------- prep ------
// 512 blocks x 256 threads. Block = 16 tokens (one s16) x half the d_model.
// tid: lo = token-within-16, dq = d-chunk. Per wave, the 64 lanes cover one
// full fragment row (16 lo x 4 g) -> coalesced 1KB frag-row stores.
__global__ __launch_bounds__(256) void prep_kernel(
    const float* __restrict__ x, const float* __restrict__ wq, const float* __restrict__ bq,
    const float* __restrict__ wk, const float* __restrict__ bk,
    ushort_t* __restrict__ Qf, ushort_t* __restrict__ Kf, ushort_t* __restrict__ xb)
{
  const int lo = threadIdx.x & 15;
  const int dq = threadIdx.x >> 4;      // 0..15
  const int blk = blockIdx.x;           // 0..511
  const int sb = blk >> 1;              // token-block 0..255
  const int half = blk & 1;
  const int tok = sb * 16 + lo;         // 0..4095 (= b*2048+s)
  const int b = tok >> 11;
  const int s16 = sb & 127;

#pragma unroll
  for (int r = 0; r < 4; ++r) {
    const int dm0 = dq * 8 + (half * 4 + r) * 128;   // 0..1016, step 8
    const int h = dm0 >> 6;
    const int dc = dm0 & 63;                         // cos-feature base
    const int e = dc >> 5, gp = (dc >> 3) & 3;
    const int bh = b * 16 + h;

    float aq[8], cq[8], ak[8], ck[8];
#pragma unroll
    for (int jj = 0; jj < 8; ++jj) {
      aq[jj] = LUTC / (1.0f + fabsf(wq[dm0 + jj]));
      cq[jj] = LUTC * bq[dm0 + jj];
      ak[jj] = LUTC / (1.0f + fabsf(wk[dm0 + jj]));
      ck[jj] = LUTC * bk[dm0 + jj];
    }
    const float4* xp4 = (const float4*)(x + (size_t)tok * 1024 + dm0);
    float4 xa = xp4[0], xbv = xp4[1];
    float xv[8] = {xa.x, xa.y, xa.z, xa.w, xbv.x, xbv.y, xbv.z, xbv.w};
    ushort_t qc[8], qs[8], kc[8], ks[8], xo[8];
#pragma unroll
    for (int jj = 0; jj < 8; ++jj) {
      int iq = ((int)rintf(fmaf(xv[jj], aq[jj], cq[jj]))) & 4095;
      float sq, cqv;
      __sincosf((float)iq * ANG, &sq, &cqv);
      int ik = ((int)rintf(fmaf(xv[jj], ak[jj], ck[jj]))) & 4095;
      float sk, ckv;
      __sincosf((float)ik * ANG, &sk, &ckv);
      qc[jj] = f2bf(cqv * QSCL);
      qs[jj] = f2bf(sq * QSCL);
      kc[jj] = f2bf(ckv);
      ks[jj] = f2bf(sk);
      xo[jj] = f2bf(xv[jj]);
    }
    size_t fb = ((size_t)bh * 128 + s16) * 4;
    size_t ln = (size_t)(gp * 16 + lo) * 8;
    store8(Qf + (fb + e) * 512 + ln, qc);        // cos -> e
    store8(Qf + (fb + 2 + e) * 512 + ln, qs);    // sin -> e+2
    store8(Kf + (fb + e) * 512 + ln, kc);
    store8(Kf + (fb + 2 + e) * 512 + ln, ks);
    store8(xb + (size_t)tok * 1024 + dm0, xo);
  }
}

// ---------------------------------------------------------------- wconv -----
__global__ __launch_bounds__(256) void wconv_kernel(
    const float* __restrict__ vw, const float* __restrict__ ow,
    ushort_t* __restrict__ vwb, ushort_t* __restrict__ owb)
{
  int t = blockIdx.x * 256 + threadIdx.x;   // 262144 threads
  const float* src;
  ushort_t* dst;
  int i;
  if (t < 131072) { src = vw; dst = vwb; i = t; }
  else            { src = ow; dst = owb; i = t - 131072; }
  const float4* p4 = (const float4*)(src + (size_t)i * 8);
  float4 a = p4[0], b = p4[1];
  float v[8] = {a.x, a.y, a.z, a.w, b.x, b.y, b.z, b.w};
  ushort_t o[8];
#pragma unroll
  for (int j = 0; j < 8; ++j) o[j] = f2bf(v[j]);
  store8(dst + (size_t)i * 8, o);
}

// ---------------------------------------------------------------- GEMM ------
// C[m][n] = sum_e A[m][e]*B[n][e]. EPI 0: f32 C[m*N+n]. EPI 1: bf16 V-frag layout.
template <int EPI>
__global__ __launch_bounds__(256) void gemm_nt(
    const ushort_t* __restrict__ A, const ushort_t* __restrict__ B,
    float* __restrict__ Cf, ushort_t* __restrict__ Cb, int M, int N, int K)
{
  __shared__ __align__(16) ushort_t As[128 * 64];
  __shared__ __align__(16) ushort_t Bs[128 * 64];
  const int l = threadIdx.x & 63;
  const int w = threadIdx.x >> 6;
  const int wm = w >> 1, wn = w & 1;
  const int mt = blockIdx.x % (M >> 7);
  const int nt = blockIdx.x / (M >> 7);
  const int m0 = mt << 7, n0 = nt << 7;

  const f32x4 zero4 = {0.f, 0.f, 0.f, 0.f};
  f32x4 acc[4][4];
#pragma unroll
  for (int i = 0; i < 4; ++i)
#pragma unroll
    for (int j = 0; j < 4; ++j) acc[i][j] = zero4;

  for (int k0 = 0; k0 < K; k0 += 64) {
#pragma unroll
    for (int i = 0; i < 4; ++i) {
      int ci = (w * 4 + i) * 64 + l;
      int r = ci >> 3, c = (ci & 7) ^ (r & 7);
      gl_lds16(A + (size_t)(m0 + r) * K + k0 + c * 8, &As[(w * 4 + i) * 512]);
      gl_lds16(B + (size_t)(n0 + r) * K + k0 + c * 8, &Bs[(w * 4 + i) * 512]);
    }
    __syncthreads();
#pragma unroll
    for (int kk = 0; kk < 2; ++kk) {
      bf16x8 af[4], bfr[4];
#pragma unroll
      for (int mi = 0; mi < 4; ++mi) {
        int r = wm * 64 + mi * 16 + (l & 15);
        int ch = ((l >> 4) + 4 * kk) ^ (r & 7);
        af[mi] = *(const bf16x8*)&As[r * 64 + ch * 8];
      }
#pragma unroll
      for (int ni = 0; ni < 4; ++ni) {
        int r = wn * 64 + ni * 16 + (l & 15);
        int ch = ((l >> 4) + 4 * kk) ^ (r & 7);
        bfr[ni] = *(const bf16x8*)&Bs[r * 64 + ch * 8];
      }
#pragma unroll
      for (int mi = 0; mi < 4; ++mi)
#pragma unroll
        for (int ni = 0; ni < 4; ++ni)
          acc[mi][ni] = __builtin_amdgcn_mfma_f32_16x16x32_bf16(af[mi], bfr[ni], acc[mi][ni], 0, 0, 0);
    }
    __syncthreads();
  }

#pragma unroll
  for (int mi = 0; mi < 4; ++mi)
#pragma unroll
    for (int ni = 0; ni < 4; ++ni)
#pragma unroll
      for (int reg = 0; reg < 4; ++reg) {
        int row = m0 + wm * 64 + mi * 16 + (l >> 4) * 4 + reg;
        int col = n0 + wn * 64 + ni * 16 + (l & 15);
        float v = acc[mi][ni][reg];
        if (EPI == 0) {
          Cf[(size_t)row * N + col] = v;
        } else {
          // V-fragment store: row = dmodel index, col = token
          int hh = row >> 6, dh = row & 63, nd = dh >> 4, lov = dh & 15;
          int bb = col >> 11, ss = col & 2047, kt = ss >> 6, sk = ss & 63;
          int kk2 = sk >> 5, gg = (sk >> 2) & 3, jj = ((sk >> 4) & 1) * 4 + (sk & 3);
          size_t o = ((((size_t)(bb * 16 + hh) * 32 + kt) * 8 + kk2 * 4 + nd) * 64
                      + gg * 16 + lov) * 8 + jj;
          Cb[o] = f2bf(v);
        }
      }
}

// ------------------------------------------------------------- attention ----
// 1024 blocks x 64 threads (1 wave). NO LDS, NO barriers. Wave = (bh, qt, h):
// 64 q-rows [qt*128+h*64, +64), k-tiles 0..2qt+h (last masked). K/V/Q read as
// coalesced dwordx4 fragments from L2 (per-XCD resident: 4 bh/XCD ~ 3MB).
// Static balance: id=(s<<8)|(j<<5)|bh -> XCD=bh&7, CU=f(j,bh); each CU's 4
// waves sum to exactly 66 k-steps.

template<bool MASKED>
__device__ __forceinline__ void attn_step64(
    const ushort_t* __restrict__ kp, const ushort_t* __restrict__ vp,
    const bf16x8 (&qf)[4][4], f32x4 (&accO)[4][4], float (&lsum)[4],
    int g, int lo)
{
  bf16x8 vf[8];
#pragma unroll
  for (int i = 0; i < 8; ++i) vf[i] = *(const bf16x8*)(vp + i * 512);

  const f32x4 zero4 = {0.f, 0.f, 0.f, 0.f};
  bf16x8 pa[4][2];
#pragma unroll
  for (int ns = 0; ns < 4; ++ns) {
    f32x4 sc[4];
#pragma unroll
    for (int qm = 0; qm < 4; ++qm) sc[qm] = zero4;
#pragma unroll
    for (int e = 0; e < 4; ++e) {
      bf16x8 kf = *(const bf16x8*)(kp + (ns * 4 + e) * 512);
#pragma unroll
      for (int qm = 0; qm < 4; ++qm)
        sc[qm] = __builtin_amdgcn_mfma_f32_16x16x32_bf16(kf, qf[qm][e], sc[qm], 0, 0, 0);
    }
#pragma unroll
    for (int qm = 0; qm < 4; ++qm)
#pragma unroll
      for (int reg = 0; reg < 4; ++reg) {
        float sv = sc[qm][reg];
        if (MASKED)
          sv = ((ns * 16 + g * 4 + reg) <= (qm * 16 + lo)) ? sv : -__builtin_inff();
        float pv = fast_exp2(sv);
        lsum[qm] += pv;
        pa[qm][ns >> 1][(ns & 1) * 4 + reg] = (__bf16)pv;
      }
  }
#pragma unroll
  for (int kk = 0; kk < 2; ++kk)
#pragma unroll
    for (int nd = 0; nd < 4; ++nd) {
      bf16x8 vv = vf[kk * 4 + nd];
#pragma unroll
      for (int qm = 0; qm < 4; ++qm)
        accO[qm][nd] = __builtin_amdgcn_mfma_f32_16x16x32_bf16(pa[qm][kk], vv, accO[qm][nd], 0, 0, 0);
    }
}

__global__ __launch_bounds__(64) void attn_kernel(
    const ushort_t* __restrict__ Qf, const ushort_t* __restrict__ Kf,
    const ushort_t* __restrict__ Vf, ushort_t* __restrict__ Ob)
{
  const int id = blockIdx.x;            // 0..1023
  const int bh = id & 31;
  const int j = (id >> 5) & 7;
  const int s = id >> 8;                // 0..3
  const int p = s >> 1;
  const int m = (j + p) & 7;
  const int qt = (s & 1) ? m : 15 - m;
  const int h2 = p;
  const int qbase = qt * 128 + h2 * 64;
  const int ntk = 2 * qt + h2 + 1;

  const int l = threadIdx.x;
  const int g = l >> 4, lo = l & 15;

  // Q fragments (coalesced frag-row loads)
  bf16x8 qf[4][4];
  {
    const ushort_t* qp = Qf + ((size_t)bh * 128 + (qbase >> 4)) * 4 * 512 + (size_t)l * 8;
#pragma unroll
    for (int qm = 0; qm < 4; ++qm)
#pragma unroll
      for (int e = 0; e < 4; ++e)
        qf[qm][e] = *(const bf16x8*)(qp + (qm * 4 + e) * 512);
  }

  const f32x4 zero4 = {0.f, 0.f, 0.f, 0.f};
  f32x4 accO[4][4];
  float lsum[4] = {0.f, 0.f, 0.f, 0.f};
#pragma unroll
  for (int qm = 0; qm < 4; ++qm)
#pragma unroll
    for (int nd = 0; nd < 4; ++nd) accO[qm][nd] = zero4;

  const ushort_t* kp = Kf + (size_t)bh * 262144 + (size_t)l * 8;  // 128*4*512
  const ushort_t* vp = Vf + (size_t)bh * 131072 + (size_t)l * 8;  // 32*8*512

  int t = 0;
  for (; t < ntk - 1; ++t)
    attn_step64<false>(kp + (size_t)t * 8192, vp + (size_t)t * 4096, qf, accO, lsum, g, lo);
  attn_step64<true>(kp + (size_t)t * 8192, vp + (size_t)t * 4096, qf, accO, lsum, g, lo);

  // row sums: reduce over the 4 g-groups, then redistribute to accO's D layout
#pragma unroll
  for (int qm = 0; qm < 4; ++qm) {
    lsum[qm] += __shfl_xor(lsum[qm], 16);
    lsum[qm] += __shfl_xor(lsum[qm], 32);
  }
  float linv[4][4];
#pragma unroll
  for (int qm = 0; qm < 4; ++qm)
#pragma unroll
    for (int reg = 0; reg < 4; ++reg)
      linv[qm][reg] = 1.0f / __shfl(lsum[qm], g * 4 + reg);

  const int b = bh >> 4, hh = bh & 15;
#pragma unroll
  for (int qm = 0; qm < 4; ++qm)
#pragma unroll
    for (int nd = 0; nd < 4; ++nd)
#pragma unroll
      for (int reg = 0; reg < 4; ++reg) {
        int q = qbase + qm * 16 + g * 4 + reg;
        int d = nd * 16 + lo;
        Ob[((size_t)(b * 2048 + q)) * 1024 + hh * 64 + d] =
            f2bf(accO[qm][nd][reg] * linv[qm][reg]);
      }
}

// ---------------------------------------------------------------- launch ----
extern "C" void kernel_launch(void* const* d_in, const int* in_sizes, int n_in,
                              void* d_out, int out_size, void* d_ws, size_t ws_size,
                              hipStream_t stream) {
  const float* x  = (const float*)d_in[0];
  const float* wq = (const float*)d_in[1];
  const float* bq = (const float*)d_in[2];
  const float* wk = (const float*)d_in[3];
  const float* bk = (const float*)d_in[4];
  const float* vw = (const float*)d_in[5];
  const float* ow = (const float*)d_in[6];
  float* out = (float*)d_out;

  char* ws = (char*)d_ws;
  ushort_t* Qfb = (ushort_t*)(ws);                      // 16 MB frag [32][128][4][64][8]
  ushort_t* Kfb = (ushort_t*)(ws + (16u << 20));        // 16 MB frag
  ushort_t* Vfb = (ushort_t*)(ws + (32u << 20));        //  8 MB frag [32][32][8][64][8]
  ushort_t* xbb = (ushort_t*)(ws + (40u << 20));        //  8 MB  [4096][1024]
  ushort_t* Obb = (ushort_t*)(ws + (48u << 20));        //  8 MB  [4096][1024]
  ushort_t* vwb = (ushort_t*)(ws + (56u << 20));        //  2 MB
  ushort_t* owb = (ushort_t*)(ws + (58u << 20));        //  2 MB

  prep_kernel<<<512, 256, 0, stream>>>(x, wq, bq, wk, bk, Qfb, Kfb, xbb);
  wconv_kernel<<<1024, 256, 0, stream>>>(vw, ow, vwb, owb);
  gemm_nt<1><<<256, 256, 0, stream>>>(vwb, xbb, nullptr, Vfb, 1024, 4096, 1024);
  attn_kernel<<<1024, 64, 0, stream>>>(Qfb, Kfb, Vfb, Obb);
  gemm_nt<0><<<256, 256, 0, stream>>>(Obb, owb, out, nullptr, 4096, 1024, 1024);
}

// Round 10
// 101.318 us; speedup vs baseline: 1.4841x; 1.4841x over previous
//
#include <hip/hip_runtime.h>
#include <hip/hip_bf16.h>
#include <math.h>

// EulerCausalAttention on MI355X (gfx950).
// prep (Q/K euler features, log2e folded into Q) ; wconv ; V-GEMM -> Vt[b,h,d,s] ;
// causal flash attention (round-7 structure: 4-wave blocks, KVBLK=64, balanced
// qt pairing, counted-vmcnt double-buffer, + setprio around compute) ;
// out-GEMM. GEMMs: 64x128 tiles (512 blocks = 2/CU) + counted-vmcnt pipeline.

typedef __attribute__((ext_vector_type(8))) __bf16 bf16x8;
typedef __attribute__((ext_vector_type(4))) __bf16 bf16x4;
typedef __attribute__((ext_vector_type(4))) float f32x4;
typedef unsigned short ushort_t;
typedef unsigned int uint_t;

#define LUTC 651.8986469044033f       // 4096 / (2*pi)
#define ANG 0.0015339807878856412f    // 2*pi / 4096
#define QSCL 0.12751743590489435f     // log2(e) / sqrt(128)  (folded into Q)

__device__ __forceinline__ float fast_exp2(float x) {
#if __has_builtin(__builtin_amdgcn_exp2f)
  return __builtin_amdgcn_exp2f(x);
#else
  return exp2f(x);
#endif
}

__device__ __forceinline__ ushort_t f2bf(float f) {
  union { __bf16 b; ushort_t u; } cv;
  cv.b = (__bf16)f;
  return cv.u;
}

__device__ __forceinline__ void store8(ushort_t* p, const ushort_t v[8]) {
  uint4 u;
  u.x = (uint_t)v[0] | ((uint_t)v[1] << 16);
  u.y = (uint_t)v[2] | ((uint_t)v[3] << 16);
  u.z = (uint_t)v[4] | ((uint_t)v[5] << 16);
  u.w = (uint_t)v[6] | ((uint_t)v[7] << 16);
  *(uint4*)p = u;
}

__device__ __forceinline__ void gl_lds16(const void* g, void* l) {
  __builtin_amdgcn_global_load_lds(
      (__attribute__((address_space(1))) void*)(g),
      (__attribute__((address_space(3))) void*)(l),
      16, 0, 0);
}

// ---------------------------------------------------------------- prep ------
__global__ __launch_bounds__(256) void prep_kernel(
    const float* __restrict__ x, const float* __restrict__ wq, const float* __restrict__ bq,
    const float* __restrict__ wk, const float* __restrict__ bk,
    ushort_t* __restrict__ Qs, ushort_t* __restrict__ Ks, ushort_t* __restrict__ xb)
{
  int t = blockIdx.x * 256 + threadIdx.x;   // 131072 threads
  int dm8 = t & 127;
  int g = t >> 7;                            // token group of 4
  int dm0 = dm8 * 8;
  int h = dm0 >> 6;

  float aq[8], cq[8], ak[8], ck[8];
#pragma unroll
  for (int j = 0; j < 8; ++j) {
    aq[j] = LUTC / (1.0f + fabsf(wq[dm0 + j]));
    cq[j] = LUTC * bq[dm0 + j];
    ak[j] = LUTC / (1.0f + fabsf(wk[dm0 + j]));
    ck[j] = LUTC * bk[dm0 + j];
  }
  for (int i = 0; i < 4; ++i) {
    int bs = g * 4 + i;
    int b = bs >> 11, s = bs & 2047;
    const float4* xp4 = (const float4*)(x + (size_t)bs * 1024 + dm0);
    float4 xa = xp4[0], xbv4 = xp4[1];
    float xv[8] = {xa.x, xa.y, xa.z, xa.w, xbv4.x, xbv4.y, xbv4.z, xbv4.w};
    ushort_t qc[8], qs[8], kc[8], ks[8], xo[8];
#pragma unroll
    for (int j = 0; j < 8; ++j) {
      int iq = ((int)rintf(fmaf(xv[j], aq[j], cq[j]))) & 4095;
      float sq, cqv;
      __sincosf((float)iq * ANG, &sq, &cqv);
      int ik = ((int)rintf(fmaf(xv[j], ak[j], ck[j]))) & 4095;
      float sk, ckv;
      __sincosf((float)ik * ANG, &sk, &ckv);
      qc[j] = f2bf(cqv * QSCL);
      qs[j] = f2bf(sq * QSCL);
      kc[j] = f2bf(ckv);
      ks[j] = f2bf(sk);
      xo[j] = f2bf(xv[j]);
    }
    size_t qb = ((size_t)(b * 16 + h) * 2048 + s) * 128 + (dm0 & 63);
    store8(Qs + qb, qc);        store8(Qs + qb + 64, qs);
    store8(Ks + qb, kc);        store8(Ks + qb + 64, ks);
    store8(xb + (size_t)bs * 1024 + dm0, xo);
  }
}

// ---------------------------------------------------------------- wconv -----
__global__ __launch_bounds__(256) void wconv_kernel(
    const float* __restrict__ vw, const float* __restrict__ ow,
    ushort_t* __restrict__ vwb, ushort_t* __restrict__ owb)
{
  int t = blockIdx.x * 256 + threadIdx.x;   // 262144 threads
  const float* src;
  ushort_t* dst;
  int i;
  if (t < 131072) { src = vw; dst = vwb; i = t; }
  else            { src = ow; dst = owb; i = t - 131072; }
  const float4* p4 = (const float4*)(src + (size_t)i * 8);
  float4 a = p4[0], b = p4[1];
  float v[8] = {a.x, a.y, a.z, a.w, b.x, b.y, b.z, b.w};
  ushort_t o[8];
#pragma unroll
  for (int j = 0; j < 8; ++j) o[j] = f2bf(v[j]);
  store8(dst + (size_t)i * 8, o);
}

// ---------------------------------------------------------------- GEMM ------
// C[m][n] = sum_e A[m][e]*B[n][e] (bf16, row-major along e).
// Tile 64(m) x 128(n), 4 waves (wave w owns n-strip w*32), K-step 64.
// 512 blocks = 2/CU. Counted-vmcnt depth-2 pipeline (no vmcnt(0) in loop).
// EPI 0: f32 C[m*N+n].  EPI 1: bf16 Vt layout (m=dmodel, n=token).
template <int EPI>
__global__ __launch_bounds__(256) void gemm_nt(
    const ushort_t* __restrict__ A, const ushort_t* __restrict__ B,
    float* __restrict__ Cf, ushort_t* __restrict__ Cb, int M, int N, int K)
{
  __shared__ __align__(16) ushort_t As[2][64 * 64];    // 2 x 8KB
  __shared__ __align__(16) ushort_t Bs[2][128 * 64];   // 2 x 16KB
  const int l = threadIdx.x & 63;
  const int w = threadIdx.x >> 6;
  const int g = l >> 4, lo = l & 15;
  const int mt = blockIdx.x % (M >> 6);
  const int nt = blockIdx.x / (M >> 6);
  const int m0 = mt << 6, n0 = nt << 7;

  const f32x4 zero4 = {0.f, 0.f, 0.f, 0.f};
  f32x4 acc[4][2];
#pragma unroll
  for (int i = 0; i < 4; ++i)
#pragma unroll
    for (int j = 0; j < 2; ++j) acc[i][j] = zero4;

  const int nk = K >> 6;   // 16 for K=1024

#define GEMM_STAGE(buf, k0_)                                                    \
  {                                                                             \
    int k0__ = (k0_);                                                           \
    _Pragma("unroll")                                                           \
    for (int i = 0; i < 2; ++i) {                                               \
      int ci = (w * 2 + i) * 64 + l;                                            \
      int r = ci >> 3, c = (ci & 7) ^ (r & 7);                                  \
      gl_lds16(A + (size_t)(m0 + r) * K + k0__ + c * 8, &As[buf][(w * 2 + i) * 512]); \
    }                                                                           \
    _Pragma("unroll")                                                           \
    for (int i = 0; i < 4; ++i) {                                               \
      int ci = (w * 4 + i) * 64 + l;                                            \
      int r = ci >> 3, c = (ci & 7) ^ (r & 7);                                  \
      gl_lds16(B + (size_t)(n0 + r) * K + k0__ + c * 8, &Bs[buf][(w * 4 + i) * 512]); \
    }                                                                           \
  }

  GEMM_STAGE(0, 0);
  GEMM_STAGE(1, 64);
  asm volatile("s_waitcnt vmcnt(6)" ::: "memory");   // tile 0 landed
  __builtin_amdgcn_s_barrier();
  __builtin_amdgcn_sched_barrier(0);

  for (int t = 0; t < nk; ++t) {
    int cb = t & 1;
#pragma unroll
    for (int kk = 0; kk < 2; ++kk) {
      bf16x8 af[4], bfr[2];
#pragma unroll
      for (int mi = 0; mi < 4; ++mi) {
        int r = mi * 16 + lo;
        int ch = (g + 4 * kk) ^ (r & 7);
        af[mi] = *(const bf16x8*)&As[cb][r * 64 + ch * 8];
      }
#pragma unroll
      for (int ni = 0; ni < 2; ++ni) {
        int r = w * 32 + ni * 16 + lo;
        int ch = (g + 4 * kk) ^ (r & 7);
        bfr[ni] = *(const bf16x8*)&Bs[cb][r * 64 + ch * 8];
      }
#pragma unroll
      for (int mi = 0; mi < 4; ++mi)
#pragma unroll
        for (int ni = 0; ni < 2; ++ni)
          acc[mi][ni] = __builtin_amdgcn_mfma_f32_16x16x32_bf16(af[mi], bfr[ni], acc[mi][ni], 0, 0, 0);
    }
    __builtin_amdgcn_sched_barrier(0);
    asm volatile("s_waitcnt lgkmcnt(0)" ::: "memory");
    __builtin_amdgcn_s_barrier();                    // all waves done reading cb
    if (t + 2 < nk) {
      GEMM_STAGE(cb, (t + 2) * 64);
      asm volatile("s_waitcnt vmcnt(6)" ::: "memory");  // tile t+1 landed
    } else {
      asm volatile("s_waitcnt vmcnt(0)" ::: "memory");
    }
    __builtin_amdgcn_s_barrier();
    __builtin_amdgcn_sched_barrier(0);
  }
#undef GEMM_STAGE

#pragma unroll
  for (int mi = 0; mi < 4; ++mi)
#pragma unroll
    for (int ni = 0; ni < 2; ++ni)
#pragma unroll
      for (int reg = 0; reg < 4; ++reg) {
        int row = m0 + mi * 16 + g * 4 + reg;
        int col = n0 + w * 32 + ni * 16 + lo;
        float v = acc[mi][ni][reg];
        if (EPI == 0) {
          Cf[(size_t)row * N + col] = v;
        } else {
          size_t o = (size_t)(col >> 11) * (1024 * 2048) + (size_t)row * 2048 + (col & 2047);
          Cb[o] = f2bf(v);
        }
      }
}

// ------------------------------------------------------------- attention ----
// Round-7 structure (current best): 512 blocks x 256 threads, 4 waves x 32
// q-rows, QBLK=128, KVBLK=64, balanced qt pairing, counted-vmcnt dbuf loop.
// Added: s_setprio(1) around the compute phase (T5).

template<bool MASKED>
__device__ __forceinline__ void attn_tile(
    const ushort_t* __restrict__ Kc, const ushort_t* __restrict__ Vc,
    const bf16x8 (&qf)[2][4], f32x4 (&accO)[2][4], f32x4 (&acc_l)[2],
    int kb, int qw, int lo, int g, const bf16x8& ones)
{
  const f32x4 zero4 = {0.f, 0.f, 0.f, 0.f};
  f32x4 sc[2][4];
#pragma unroll
  for (int qm = 0; qm < 2; ++qm)
#pragma unroll
    for (int ns = 0; ns < 4; ++ns) sc[qm][ns] = zero4;

  // S^T tile: lane holds S[q=qw+qm*16+lo][k=kb+ns*16+g*4+reg]
#pragma unroll
  for (int e = 0; e < 4; ++e) {
#pragma unroll
    for (int ns = 0; ns < 4; ++ns) {
      int kr = ns * 16 + lo;
      int cc = (g + 4 * e) ^ (kr & 7);
      bf16x8 kf = *(const bf16x8*)&Kc[kr * 128 + cc * 8];
#pragma unroll
      for (int qm = 0; qm < 2; ++qm)
        sc[qm][ns] = __builtin_amdgcn_mfma_f32_16x16x32_bf16(kf, qf[qm][e], sc[qm][ns], 0, 0, 0);
    }
  }

  // p = exp2(s), pack to PV A-fragments (registers only)
  bf16x8 pa[2][2];
#pragma unroll
  for (int qm = 0; qm < 2; ++qm) {
#pragma unroll
    for (int ns = 0; ns < 4; ++ns) {
#pragma unroll
      for (int reg = 0; reg < 4; ++reg) {
        float sv = sc[qm][ns][reg];
        if (MASKED) {
          int ka = kb + ns * 16 + g * 4 + reg;
          int qa = qw + qm * 16 + lo;
          sv = (ka <= qa) ? sv : -__builtin_inff();
        }
        pa[qm][ns >> 1][(ns & 1) * 4 + reg] = (__bf16)fast_exp2(sv);
      }
    }
  }

  // O += P V ; rowsum += P * ones
#pragma unroll
  for (int kk = 0; kk < 2; ++kk) {
#pragma unroll
    for (int nd = 0; nd < 4; ++nd) {
      int vr = nd * 16 + lo;
      int h8 = (g & 1) * 4;
      int cc0 = (4 * kk + (g >> 1)) ^ (vr & 7);
      int cc1 = (4 * kk + 2 + (g >> 1)) ^ (vr & 7);
      union { bf16x8 v8; bf16x4 v4[2]; } u;
      u.v4[0] = *(const bf16x4*)&Vc[vr * 64 + cc0 * 8 + h8];
      u.v4[1] = *(const bf16x4*)&Vc[vr * 64 + cc1 * 8 + h8];
#pragma unroll
      for (int qm = 0; qm < 2; ++qm)
        accO[qm][nd] = __builtin_amdgcn_mfma_f32_16x16x32_bf16(pa[qm][kk], u.v8, accO[qm][nd], 0, 0, 0);
    }
#pragma unroll
    for (int qm = 0; qm < 2; ++qm)
      acc_l[qm] = __builtin_amdgcn_mfma_f32_16x16x32_bf16(pa[qm][kk], ones, acc_l[qm], 0, 0, 0);
  }
}

__global__ __launch_bounds__(256) void attn_kernel(
    const ushort_t* __restrict__ Qs, const ushort_t* __restrict__ Ks,
    const ushort_t* __restrict__ Vt, ushort_t* __restrict__ Ob)
{
  const int S = 2048;
  const int id = blockIdx.x;                 // 0..511
  const int bh = id & 31;
  const int qt = (id < 256) ? (15 - (id >> 5)) : ((id - 256) >> 5);
  const int l = threadIdx.x & 63;
  const int w = threadIdx.x >> 6;
  const int g = l >> 4, lo = l & 15;

  __shared__ __align__(16) ushort_t Kl[2][64 * 128];  // 2 x 16KB
  __shared__ __align__(16) ushort_t Vl[2][64 * 64];   // 2 x 8KB

  const int q0b = qt * 128;
  const int qw = q0b + w * 32;
  const ushort_t* Kbase = Ks + (size_t)bh * S * 128;
  const ushort_t* Vbase = Vt + (size_t)bh * 64 * S;

  bf16x8 ones;
#pragma unroll
  for (int j = 0; j < 8; ++j) ones[j] = (__bf16)1.0f;

  // Q fragments: qf[qm][e] = Q[qw+qm*16+lo][32e+8g .. +7]
  bf16x8 qf[2][4];
#pragma unroll
  for (int qm = 0; qm < 2; ++qm) {
    const ushort_t* qp = Qs + ((size_t)bh * S + qw + qm * 16 + lo) * 128 + 8 * g;
#pragma unroll
    for (int e = 0; e < 4; ++e) qf[qm][e] = *(const bf16x8*)(qp + 32 * e);
  }

  const f32x4 zero4 = {0.f, 0.f, 0.f, 0.f};
  f32x4 accO[2][4];
  f32x4 acc_l[2];
#pragma unroll
  for (int qm = 0; qm < 2; ++qm) {
    acc_l[qm] = zero4;
#pragma unroll
    for (int nd = 0; nd < 4; ++nd) accO[qm][nd] = zero4;
  }

  const int nt = 2 * qt + 2;   // >= 2 always

#define ATTN_STAGE(buf, kb_)                                                    \
  {                                                                             \
    int kb__ = (kb_);                                                           \
    _Pragma("unroll")                                                           \
    for (int i = 0; i < 4; ++i) {                                               \
      int ci = (w * 4 + i) * 64 + l;                                            \
      int r = ci >> 4, c = (ci & 15) ^ (r & 7);                                 \
      gl_lds16(Kbase + (size_t)(kb__ + r) * 128 + c * 8, &Kl[buf][(w * 4 + i) * 512]); \
    }                                                                           \
    _Pragma("unroll")                                                           \
    for (int i = 0; i < 2; ++i) {                                               \
      int ci = (w * 2 + i) * 64 + l;                                            \
      int r = ci >> 3, c = (ci & 7) ^ (r & 7);                                  \
      gl_lds16(Vbase + (size_t)r * S + kb__ + c * 8, &Vl[buf][(w * 2 + i) * 512]); \
    }                                                                           \
  }

  // prologue: stage tiles 0 and 1; confirm tile 0 (6 newest = tile 1 in flight)
  ATTN_STAGE(0, 0);
  ATTN_STAGE(1, 64);
  asm volatile("s_waitcnt vmcnt(6)" ::: "memory");
  __builtin_amdgcn_s_barrier();
  __builtin_amdgcn_sched_barrier(0);

  for (int t = 0; t < nt; ++t) {
    int cb = t & 1;
    __builtin_amdgcn_s_setprio(1);
    if (t < 2 * qt)
      attn_tile<false>(Kl[cb], Vl[cb], qf, accO, acc_l, t * 64, qw, lo, g, ones);
    else
      attn_tile<true>(Kl[cb], Vl[cb], qf, accO, acc_l, t * 64, qw, lo, g, ones);
    __builtin_amdgcn_s_setprio(0);
    __builtin_amdgcn_sched_barrier(0);
    asm volatile("s_waitcnt lgkmcnt(0)" ::: "memory");
    __builtin_amdgcn_s_barrier();            // all waves done reading buf cb
    if (t + 2 < nt) {
      ATTN_STAGE(cb, (t + 2) * 64);          // refill the buffer just freed
      asm volatile("s_waitcnt vmcnt(6)" ::: "memory");   // stage(t+1) landed
    } else {
      asm volatile("s_waitcnt vmcnt(0)" ::: "memory");   // tail: drain rest
    }
    __builtin_amdgcn_s_barrier();            // publish stage(t+1) completion
    __builtin_amdgcn_sched_barrier(0);
  }
#undef ATTN_STAGE

  // normalize: acc_l layout == accO layout (row=(l>>4)*4+reg, replicated cols)
  float linv[2][4];
#pragma unroll
  for (int qm = 0; qm < 2; ++qm)
#pragma unroll
    for (int reg = 0; reg < 4; ++reg)
      linv[qm][reg] = 1.0f / acc_l[qm][reg];

  const int b = bh >> 4, h = bh & 15;
#pragma unroll
  for (int qm = 0; qm < 2; ++qm)
#pragma unroll
    for (int nd = 0; nd < 4; ++nd)
#pragma unroll
      for (int reg = 0; reg < 4; ++reg) {
        int q = qw + qm * 16 + g * 4 + reg;
        int d = nd * 16 + lo;
        Ob[((size_t)(b * 2048 + q)) * 1024 + h * 64 + d] = f2bf(accO[qm][nd][reg] * linv[qm][reg]);
      }
}

// ---------------------------------------------------------------- launch ----
extern "C" void kernel_launch(void* const* d_in, const int* in_sizes, int n_in,
                              void* d_out, int out_size, void* d_ws, size_t ws_size,
                              hipStream_t stream) {
  const float* x  = (const float*)d_in[0];
  const float* wq = (const float*)d_in[1];
  const float* bq = (const float*)d_in[2];
  const float* wk = (const float*)d_in[3];
  const float* bk = (const float*)d_in[4];
  const float* vw = (const float*)d_in[5];
  const float* ow = (const float*)d_in[6];
  float* out = (float*)d_out;

  char* ws = (char*)d_ws;
  ushort_t* Qs  = (ushort_t*)(ws);                      // 16 MB  [32][2048][128]
  ushort_t* Ksb = (ushort_t*)(ws + (16u << 20));        // 16 MB  [32][2048][128]
  ushort_t* Vtb = (ushort_t*)(ws + (32u << 20));        //  8 MB  [32][64][2048]
  ushort_t* xbb = (ushort_t*)(ws + (40u << 20));        //  8 MB  [4096][1024]
  ushort_t* Obb = (ushort_t*)(ws + (48u << 20));        //  8 MB  [4096][1024]
  ushort_t* vwb = (ushort_t*)(ws + (56u << 20));        //  2 MB
  ushort_t* owb = (ushort_t*)(ws + (58u << 20));        //  2 MB

  prep_kernel<<<512, 256, 0, stream>>>(x, wq, bq, wk, bk, Qs, Ksb, xbb);
  wconv_kernel<<<1024, 256, 0, stream>>>(vw, ow, vwb, owb);
  gemm_nt<1><<<512, 256, 0, stream>>>(vwb, xbb, nullptr, Vtb, 1024, 4096, 1024);
  attn_kernel<<<512, 256, 0, stream>>>(Qs, Ksb, Vtb, Obb);
  gemm_nt<0><<<512, 256, 0, stream>>>(Obb, owb, out, nullptr, 4096, 1024, 1024);
}